// Round 1
// baseline (2837.237 us; speedup 1.0000x reference)
//
#include <hip/hip_runtime.h>

#define NN 50000
#define NE 400000
#define NG 256
#define BN_EPS 1e-5f

// ---------------- GEMM: C[M x 128] = A[M x K] @ W[K x 128] (+bias)(ReLU) ----
template<bool BIAS, bool RELU>
__global__ __launch_bounds__(256)
void gemm128(const float* __restrict__ A, const float* __restrict__ W,
             const float* __restrict__ bias, float* __restrict__ C,
             int M, int K) {
  __shared__ float xs[128][17];
  __shared__ float ws[16][132];
  const int t = threadIdx.x;
  const int row0 = blockIdx.x * 128;
  const int tr = t >> 4, tc = t & 15;
  float acc[8][8] = {};
  for (int k0 = 0; k0 < K; k0 += 16) {
#pragma unroll
    for (int i = 0; i < 8; ++i) {
      int idx = t + i * 256;
      int r = idx >> 4, kk = idx & 15;
      int gr = row0 + r, gk = k0 + kk;
      xs[r][kk] = (gr < M && gk < K) ? A[(long)gr * K + gk] : 0.f;
    }
#pragma unroll
    for (int i = 0; i < 8; ++i) {
      int idx = t + i * 256;
      int kk = idx >> 7, c = idx & 127;
      int gk = k0 + kk;
      ws[kk][c] = (gk < K) ? W[(long)gk * 128 + c] : 0.f;
    }
    __syncthreads();
#pragma unroll
    for (int kk = 0; kk < 16; ++kk) {
      float xv[8], wv[8];
#pragma unroll
      for (int r = 0; r < 8; ++r) xv[r] = xs[tr * 8 + r][kk];
#pragma unroll
      for (int j = 0; j < 8; ++j) wv[j] = ws[kk][tc * 8 + j];
#pragma unroll
      for (int r = 0; r < 8; ++r)
#pragma unroll
        for (int j = 0; j < 8; ++j)
          acc[r][j] += xv[r] * wv[j];
    }
    __syncthreads();
  }
#pragma unroll
  for (int r = 0; r < 8; ++r) {
    int gr = row0 + tr * 8 + r;
    if (gr < M) {
#pragma unroll
      for (int j = 0; j < 8; ++j) {
        int c = tc * 8 + j;
        float v = acc[r][j];
        if (BIAS) v += bias[c];
        if (RELU) v = fmaxf(v, 0.f);
        C[(long)gr * 128 + c] = v;
      }
    }
  }
}

// ---------------- edge aggregation: agg[dst] += y[src]  (128 feats) --------
__global__ __launch_bounds__(256)
void agg_atomic(const float* __restrict__ y, const int* __restrict__ src,
                const int* __restrict__ dst, float* __restrict__ agg, int E) {
  long idx = (long)blockIdx.x * 256 + threadIdx.x;
  long total = (long)E * 32;
  if (idx >= total) return;
  int e = (int)(idx >> 5);
  int c4 = (int)(idx & 31);
  int s = src[e], d = dst[e];
  const float4 v = ((const float4*)y)[(long)s * 32 + c4];
  float* base = agg + (long)d * 128 + c4 * 4;
  atomicAdd(base + 0, v.x);
  atomicAdd(base + 1, v.y);
  atomicAdd(base + 2, v.z);
  atomicAdd(base + 3, v.w);
}

// ---------------- BN(eval)+ReLU with b1 folded in, in-place into y ---------
__global__ __launch_bounds__(256)
void bn_relu(float* __restrict__ y, const float* __restrict__ agg,
             const float* __restrict__ b1, const float* __restrict__ g,
             const float* __restrict__ bb, const float* __restrict__ m,
             const float* __restrict__ v, int n4) {
  int idx = blockIdx.x * 256 + threadIdx.x;
  if (idx >= n4) return;
  int c4 = idx & 31;
  float4 gv = ((const float4*)g)[c4];
  float4 bbv = ((const float4*)bb)[c4];
  float4 mv = ((const float4*)m)[c4];
  float4 vv = ((const float4*)v)[c4];
  float4 b1v = ((const float4*)b1)[c4];
  float4 yv = ((const float4*)y)[idx];
  float4 av = ((const float4*)agg)[idx];
  float s0 = gv.x * rsqrtf(vv.x + BN_EPS);
  float s1 = gv.y * rsqrtf(vv.y + BN_EPS);
  float s2 = gv.z * rsqrtf(vv.z + BN_EPS);
  float s3 = gv.w * rsqrtf(vv.w + BN_EPS);
  float4 o;
  o.x = fmaxf((yv.x + av.x + b1v.x - mv.x) * s0 + bbv.x, 0.f);
  o.y = fmaxf((yv.y + av.y + b1v.y - mv.y) * s1 + bbv.y, 0.f);
  o.z = fmaxf((yv.z + av.z + b1v.z - mv.z) * s2 + bbv.z, 0.f);
  o.w = fmaxf((yv.w + av.w + b1v.w - mv.w) * s3 + bbv.w, 0.f);
  ((float4*)y)[idx] = o;
}

// ---------------- graph boundaries via binary search (batch is sorted) -----
__global__ void graph_bounds(const int* __restrict__ batch, int* __restrict__ gstart, int n) {
  int g = blockIdx.x * 64 + threadIdx.x;
  if (g > NG) return;
  int lo = 0, hi = n;
  while (lo < hi) {
    int mid = (lo + hi) >> 1;
    if (batch[mid] < g) lo = mid + 1; else hi = mid;
  }
  gstart[g] = lo;
}

// ---------------- mean pool of one h layer into pooled[:, layer*128:...] ---
__global__ __launch_bounds__(128)
void pool_mean(const float* __restrict__ h, const int* __restrict__ gstart,
               float* __restrict__ pooled, int layer) {
  int g = blockIdx.x, c = threadIdx.x;
  int s = gstart[g], e = gstart[g + 1];
  float acc = 0.f;
  for (int i = s; i < e; ++i) acc += h[(long)i * 128 + c];
  pooled[g * 384 + layer * 128 + c] = acc / fmaxf((float)(e - s), 1.f);
}

// ---------------- lin1: z = ReLU(pooled @ W + b), 256x384x384 --------------
__global__ __launch_bounds__(384)
void lin1_k(const float* __restrict__ pooled, const float* __restrict__ w,
            const float* __restrict__ b, float* __restrict__ z) {
  __shared__ float pr[384];
  int mrow = blockIdx.x, t = threadIdx.x;
  pr[t] = pooled[mrow * 384 + t];
  __syncthreads();
  float acc = b[t];
  for (int k = 0; k < 384; ++k) acc += pr[k] * w[k * 384 + t];
  z[mrow * 384 + t] = fmaxf(acc, 0.f);
}

// ---------------- lin2: out = z @ W + b, 256x384x3 -------------------------
__global__ __launch_bounds__(192)
void lin2_k(const float* __restrict__ z, const float* __restrict__ w,
            const float* __restrict__ b, float* __restrict__ out) {
  int idx = blockIdx.x * 192 + threadIdx.x;
  if (idx >= NG * 3) return;
  int mrow = idx / 3, j = idx % 3;
  float acc = b[j];
  for (int k = 0; k < 384; ++k) acc += z[mrow * 384 + k] * w[k * 3 + j];
  out[idx] = acc;
}

extern "C" void kernel_launch(void* const* d_in, const int* in_sizes, int n_in,
                              void* d_out, int out_size, void* d_ws, size_t ws_size,
                              hipStream_t stream) {
  const float* x = (const float*)d_in[0];
  const int* ei = (const int*)d_in[1];
  const int* batch = (const int*)d_in[2];
  const int* srcv = ei;
  const int* dstv = ei + NE;
  const float* cw1[3] = {(const float*)d_in[3], (const float*)d_in[11], (const float*)d_in[19]};
  const float* cb1[3] = {(const float*)d_in[4], (const float*)d_in[12], (const float*)d_in[20]};
  const float* cg[3]  = {(const float*)d_in[5], (const float*)d_in[13], (const float*)d_in[21]};
  const float* cbb[3] = {(const float*)d_in[6], (const float*)d_in[14], (const float*)d_in[22]};
  const float* cm[3]  = {(const float*)d_in[7], (const float*)d_in[15], (const float*)d_in[23]};
  const float* cv[3]  = {(const float*)d_in[8], (const float*)d_in[16], (const float*)d_in[24]};
  const float* cw2[3] = {(const float*)d_in[9], (const float*)d_in[17], (const float*)d_in[25]};
  const float* cb2[3] = {(const float*)d_in[10], (const float*)d_in[18], (const float*)d_in[26]};
  const float* lin1_w = (const float*)d_in[27];
  const float* lin1_b = (const float*)d_in[28];
  const float* lin2_w = (const float*)d_in[29];
  const float* lin2_b = (const float*)d_in[30];

  float* wsf = (float*)d_ws;
  float* y = wsf;                       // N*128
  float* agg = y + (size_t)NN * 128;    // N*128
  float* h[3];
  h[0] = agg + (size_t)NN * 128;
  h[1] = h[0] + (size_t)NN * 128;
  h[2] = h[1] + (size_t)NN * 128;
  float* pooled = h[2] + (size_t)NN * 128;   // 256*384
  float* z = pooled + (size_t)NG * 384;      // 256*384
  int* gstart = (int*)(z + (size_t)NG * 384); // 257 ints

  const int gemm_grid = (NN + 127) / 128;
  const long agg_items = (long)NE * 32;
  const int n4 = NN * 32;

  for (int c = 0; c < 3; ++c) {
    const float* in = (c == 0) ? x : h[c - 1];
    int K = (c == 0) ? 513 : 128;
    // y = in @ W1  (no bias; bias folded into BN shift)
    gemm128<false, false><<<gemm_grid, 256, 0, stream>>>(in, cw1[c], nullptr, y, NN, K);
    hipMemsetAsync(agg, 0, (size_t)NN * 128 * sizeof(float), stream);
    agg_atomic<<<(int)((agg_items + 255) / 256), 256, 0, stream>>>(y, srcv, dstv, agg, NE);
    bn_relu<<<(n4 + 255) / 256, 256, 0, stream>>>(y, agg, cb1[c], cg[c], cbb[c], cm[c], cv[c], n4);
    // h[c] = ReLU(y @ W2 + b2)
    gemm128<true, true><<<gemm_grid, 256, 0, stream>>>(y, cw2[c], cb2[c], h[c], NN, 128);
  }
  graph_bounds<<<5, 64, 0, stream>>>(batch, gstart, NN);
  for (int l = 0; l < 3; ++l)
    pool_mean<<<NG, 128, 0, stream>>>(h[l], gstart, pooled, l);
  lin1_k<<<NG, 384, 0, stream>>>(pooled, lin1_w, lin1_b, z);
  lin2_k<<<4, 192, 0, stream>>>(z, lin2_w, lin2_b, (float*)d_out);
}

// Round 2
// 940.930 us; speedup vs baseline: 3.0154x; 3.0154x over previous
//
#include <hip/hip_runtime.h>

#define NN 50000
#define NE 400000
#define NG 256
#define BN_EPS 1e-5f
#define SCAN_E 8
#define SCAN_CHUNK 2048           // 256 threads * 8
#define SCAN_NB 25                // ceil(50000/2048)

// ---------------- GEMM: C[M x 128] = A[M x K] @ W[K x 128] (+bias)(ReLU) ----
template<bool BIAS, bool RELU>
__global__ __launch_bounds__(256)
void gemm128(const float* __restrict__ A, const float* __restrict__ W,
             const float* __restrict__ bias, float* __restrict__ C,
             int M, int K) {
  __shared__ float xs[128][17];
  __shared__ float ws[16][132];
  const int t = threadIdx.x;
  const int row0 = blockIdx.x * 128;
  const int tr = t >> 4, tc = t & 15;
  float acc[8][8] = {};
  for (int k0 = 0; k0 < K; k0 += 16) {
#pragma unroll
    for (int i = 0; i < 8; ++i) {
      int idx = t + i * 256;
      int r = idx >> 4, kk = idx & 15;
      int gr = row0 + r, gk = k0 + kk;
      xs[r][kk] = (gr < M && gk < K) ? A[(long)gr * K + gk] : 0.f;
    }
#pragma unroll
    for (int i = 0; i < 8; ++i) {
      int idx = t + i * 256;
      int kk = idx >> 7, c = idx & 127;
      int gk = k0 + kk;
      ws[kk][c] = (gk < K) ? W[(long)gk * 128 + c] : 0.f;
    }
    __syncthreads();
#pragma unroll
    for (int kk = 0; kk < 16; ++kk) {
      float xv[8], wv[8];
#pragma unroll
      for (int r = 0; r < 8; ++r) xv[r] = xs[tr * 8 + r][kk];
#pragma unroll
      for (int j = 0; j < 8; ++j) wv[j] = ws[kk][tc * 8 + j];
#pragma unroll
      for (int r = 0; r < 8; ++r)
#pragma unroll
        for (int j = 0; j < 8; ++j)
          acc[r][j] += xv[r] * wv[j];
    }
    __syncthreads();
  }
#pragma unroll
  for (int r = 0; r < 8; ++r) {
    int gr = row0 + tr * 8 + r;
    if (gr < M) {
#pragma unroll
      for (int j = 0; j < 8; ++j) {
        int c = tc * 8 + j;
        float v = acc[r][j];
        if (BIAS) v += bias[c];
        if (RELU) v = fmaxf(v, 0.f);
        C[(long)gr * 128 + c] = v;
      }
    }
  }
}

// ---------------- CSR build -------------------------------------------------
__global__ __launch_bounds__(256)
void deg_count(const int* __restrict__ dst, int* __restrict__ deg, int E) {
  int e = blockIdx.x * 256 + threadIdx.x;
  if (e < E) atomicAdd(&deg[dst[e]], 1);
}

__global__ __launch_bounds__(256)
void scan_sums(const int* __restrict__ deg, int* __restrict__ bsum) {
  __shared__ int sm[256];
  int base = blockIdx.x * SCAN_CHUNK + threadIdx.x * SCAN_E;
  int s = 0;
#pragma unroll
  for (int k = 0; k < SCAN_E; ++k) { int i = base + k; if (i < NN) s += deg[i]; }
  sm[threadIdx.x] = s; __syncthreads();
  for (int off = 128; off > 0; off >>= 1) {
    if (threadIdx.x < off) sm[threadIdx.x] += sm[threadIdx.x + off];
    __syncthreads();
  }
  if (threadIdx.x == 0) bsum[blockIdx.x] = sm[0];
}

__global__ void scan_offs(const int* __restrict__ bsum, int* __restrict__ boff,
                          int* __restrict__ rowptr) {
  if (threadIdx.x == 0) {
    int run = 0;
    for (int i = 0; i < SCAN_NB; ++i) { boff[i] = run; run += bsum[i]; }
    rowptr[NN] = run;
  }
}

__global__ __launch_bounds__(256)
void scan_final(const int* __restrict__ boff, int* __restrict__ rowptr,
                int* __restrict__ cursor) {
  __shared__ int sm[256];
  int t = threadIdx.x;
  int base = blockIdx.x * SCAN_CHUNK + t * SCAN_E;
  int v[SCAN_E]; int s = 0;
#pragma unroll
  for (int k = 0; k < SCAN_E; ++k) { int i = base + k; v[k] = (i < NN) ? rowptr[i] : 0; s += v[k]; }
  sm[t] = s; __syncthreads();
  for (int off = 1; off < 256; off <<= 1) {
    int val = sm[t]; int add = (t >= off) ? sm[t - off] : 0;
    __syncthreads();
    sm[t] = val + add;
    __syncthreads();
  }
  int excl = (t == 0 ? 0 : sm[t - 1]) + boff[blockIdx.x];
#pragma unroll
  for (int k = 0; k < SCAN_E; ++k) {
    int i = base + k;
    if (i < NN) { rowptr[i] = excl; cursor[i] = excl; }
    excl += v[k];
  }
}

__global__ __launch_bounds__(256)
void scatter_csr(const int* __restrict__ src, const int* __restrict__ dst,
                 int* __restrict__ cursor, int* __restrict__ csr_src, int E) {
  int e = blockIdx.x * 256 + threadIdx.x;
  if (e < E) {
    int d = dst[e];
    int pos = atomicAdd(&cursor[d], 1);
    csr_src[pos] = src[e];
  }
}

// ---------------- fold BN params --------------------------------------------
__global__ void bn_prep(const float* __restrict__ b1, const float* __restrict__ g,
                        const float* __restrict__ bb, const float* __restrict__ m,
                        const float* __restrict__ v, float* __restrict__ scale,
                        float* __restrict__ shift) {
  int c = threadIdx.x;
  float s = g[c] * rsqrtf(v[c] + BN_EPS);
  scale[c] = s;
  shift[c] = (b1[c] - m[c]) * s + bb[c];
}

// ------- gather+sum over in-edges, fused BN+ReLU: out = ReLU((y_i+Σy_j)*sc+sh)
__global__ __launch_bounds__(256)
void gather_bn(const float* __restrict__ y, const int* __restrict__ rowptr,
               const int* __restrict__ csr_src, const float* __restrict__ scale,
               const float* __restrict__ shift, float* __restrict__ out) {
  const int grp = threadIdx.x >> 5;        // 8 node-groups per block
  const int lane = threadIdx.x & 31;       // 32 lanes = 32 float4 = 128 feats
  const int node = blockIdx.x * 8 + grp;
  if (node >= NN) return;
  const float4* y4 = (const float4*)y;
  int s = rowptr[node], e = rowptr[node + 1];
  float4 acc = y4[(long)node * 32 + lane];  // self term (eps=0)
  for (int i = s; i < e; ++i) {
    int sn = csr_src[i];
    float4 v = y4[(long)sn * 32 + lane];
    acc.x += v.x; acc.y += v.y; acc.z += v.z; acc.w += v.w;
  }
  float4 sc = ((const float4*)scale)[lane];
  float4 sh = ((const float4*)shift)[lane];
  float4 o;
  o.x = fmaxf(acc.x * sc.x + sh.x, 0.f);
  o.y = fmaxf(acc.y * sc.y + sh.y, 0.f);
  o.z = fmaxf(acc.z * sc.z + sh.z, 0.f);
  o.w = fmaxf(acc.w * sc.w + sh.w, 0.f);
  ((float4*)out)[(long)node * 32 + lane] = o;
}

// ---------------- graph boundaries via binary search (batch is sorted) -----
__global__ void graph_bounds(const int* __restrict__ batch, int* __restrict__ gstart, int n) {
  int g = blockIdx.x * 64 + threadIdx.x;
  if (g > NG) return;
  int lo = 0, hi = n;
  while (lo < hi) {
    int mid = (lo + hi) >> 1;
    if (batch[mid] < g) lo = mid + 1; else hi = mid;
  }
  gstart[g] = lo;
}

__global__ __launch_bounds__(128)
void pool_mean(const float* __restrict__ h, const int* __restrict__ gstart,
               float* __restrict__ pooled, int layer) {
  int g = blockIdx.x, c = threadIdx.x;
  int s = gstart[g], e = gstart[g + 1];
  float acc = 0.f;
  for (int i = s; i < e; ++i) acc += h[(long)i * 128 + c];
  pooled[g * 384 + layer * 128 + c] = acc / fmaxf((float)(e - s), 1.f);
}

__global__ __launch_bounds__(384)
void lin1_k(const float* __restrict__ pooled, const float* __restrict__ w,
            const float* __restrict__ b, float* __restrict__ z) {
  __shared__ float pr[384];
  int mrow = blockIdx.x, t = threadIdx.x;
  pr[t] = pooled[mrow * 384 + t];
  __syncthreads();
  float acc = b[t];
  for (int k = 0; k < 384; ++k) acc += pr[k] * w[k * 384 + t];
  z[mrow * 384 + t] = fmaxf(acc, 0.f);
}

__global__ __launch_bounds__(192)
void lin2_k(const float* __restrict__ z, const float* __restrict__ w,
            const float* __restrict__ b, float* __restrict__ out) {
  int idx = blockIdx.x * 192 + threadIdx.x;
  if (idx >= NG * 3) return;
  int mrow = idx / 3, j = idx % 3;
  float acc = b[j];
  for (int k = 0; k < 384; ++k) acc += z[mrow * 384 + k] * w[k * 3 + j];
  out[idx] = acc;
}

extern "C" void kernel_launch(void* const* d_in, const int* in_sizes, int n_in,
                              void* d_out, int out_size, void* d_ws, size_t ws_size,
                              hipStream_t stream) {
  const float* x = (const float*)d_in[0];
  const int* ei = (const int*)d_in[1];
  const int* batch = (const int*)d_in[2];
  const int* srcv = ei;
  const int* dstv = ei + NE;
  const float* cw1[3] = {(const float*)d_in[3], (const float*)d_in[11], (const float*)d_in[19]};
  const float* cb1[3] = {(const float*)d_in[4], (const float*)d_in[12], (const float*)d_in[20]};
  const float* cg[3]  = {(const float*)d_in[5], (const float*)d_in[13], (const float*)d_in[21]};
  const float* cbb[3] = {(const float*)d_in[6], (const float*)d_in[14], (const float*)d_in[22]};
  const float* cm[3]  = {(const float*)d_in[7], (const float*)d_in[15], (const float*)d_in[23]};
  const float* cv[3]  = {(const float*)d_in[8], (const float*)d_in[16], (const float*)d_in[24]};
  const float* cw2[3] = {(const float*)d_in[9], (const float*)d_in[17], (const float*)d_in[25]};
  const float* cb2[3] = {(const float*)d_in[10], (const float*)d_in[18], (const float*)d_in[26]};
  const float* lin1_w = (const float*)d_in[27];
  const float* lin1_b = (const float*)d_in[28];
  const float* lin2_w = (const float*)d_in[29];
  const float* lin2_b = (const float*)d_in[30];

  const size_t NNF = (size_t)NN * 128;
  float* wsf = (float*)d_ws;
  float* y    = wsf;               // NN*128
  float* hpre = y + NNF;           // NN*128 (gather+BN output)
  float* h0   = hpre + NNF;        // NN*128
  float* h1   = h0 + NNF;          // NN*128
  float* h2   = y;                 // alias: y is free after conv3's gather
  float* hbuf[3] = {h0, h1, h2};
  float* pooled = hpre;            // alias: hpre free after conv3's gemm2
  float* z = pooled + (size_t)NG * 384;
  int* rowptr  = (int*)(h1 + NNF); // NN+1  (doubles as deg before scan)
  int* cursor  = rowptr + NN + 1;  // NN
  int* csr_src = cursor + NN;      // NE
  int* bsum    = csr_src + NE;     // 25
  int* boff    = bsum + 32;        // 26
  int* gstart  = boff + 64;        // 257
  float* scale = (float*)(gstart + 260);
  float* shift = scale + 128;

  // ---- build CSR (by dst) once; reused by all 3 layers ----
  hipMemsetAsync(rowptr, 0, (NN + 1) * sizeof(int), stream);
  deg_count<<<(NE + 255) / 256, 256, 0, stream>>>(dstv, rowptr, NE);
  scan_sums<<<SCAN_NB, 256, 0, stream>>>(rowptr, bsum);
  scan_offs<<<1, 64, 0, stream>>>(bsum, boff, rowptr);
  scan_final<<<SCAN_NB, 256, 0, stream>>>(boff, rowptr, cursor);
  scatter_csr<<<(NE + 255) / 256, 256, 0, stream>>>(srcv, dstv, cursor, csr_src, NE);

  const int gemm_grid = (NN + 127) / 128;
  for (int c = 0; c < 3; ++c) {
    const float* in = (c == 0) ? x : hbuf[c - 1];
    int K = (c == 0) ? 513 : 128;
    bn_prep<<<1, 128, 0, stream>>>(cb1[c], cg[c], cbb[c], cm[c], cv[c], scale, shift);
    gemm128<false, false><<<gemm_grid, 256, 0, stream>>>(in, cw1[c], nullptr, y, NN, K);
    gather_bn<<<(NN + 7) / 8, 256, 0, stream>>>(y, rowptr, csr_src, scale, shift, hpre);
    gemm128<true, true><<<gemm_grid, 256, 0, stream>>>(hpre, cw2[c], cb2[c], hbuf[c], NN, 128);
  }
  graph_bounds<<<5, 64, 0, stream>>>(batch, gstart, NN);
  for (int l = 0; l < 3; ++l)
    pool_mean<<<NG, 128, 0, stream>>>(hbuf[l], gstart, pooled, l);
  lin1_k<<<NG, 384, 0, stream>>>(pooled, lin1_w, lin1_b, z);
  lin2_k<<<4, 192, 0, stream>>>(z, lin2_w, lin2_b, (float*)d_out);
}

// Round 3
// 542.954 us; speedup vs baseline: 5.2256x; 1.7330x over previous
//
#include <hip/hip_runtime.h>

#define NN 50000
#define NE 400000
#define NG 256
#define BN_EPS 1e-5f
#define SCAN_E 8
#define SCAN_CHUNK 2048           // 256 threads * 8
#define SCAN_NB 25                // ceil(50000/2048)

typedef __attribute__((ext_vector_type(4))) float f32x4;
typedef __bf16 bf16x8 __attribute__((ext_vector_type(8)));

__device__ __forceinline__ void mfma_bf16(f32x4& d, bf16x8 a, bf16x8 b) {
  asm volatile("v_mfma_f32_16x16x32_bf16 %0, %1, %2, %0" : "+v"(d) : "v"(a), "v"(b));
}

// ---- W pre-split: wh/wl[n][k] = bf16 hi/lo of W[k][n], zero-padded to Kpad --
__global__ __launch_bounds__(256)
void wprep(const float* __restrict__ W, __bf16* __restrict__ wh,
           __bf16* __restrict__ wl, int K, int Kpad) {
  int idx = blockIdx.x * 256 + threadIdx.x;
  if (idx >= 128 * Kpad) return;
  int n = idx & 127, k = idx >> 7;
  float v = (k < K) ? W[(long)k * 128 + n] : 0.f;
  __bf16 h = (__bf16)v;
  float r = v - (float)h;
  wh[(long)n * Kpad + k] = h;
  wl[(long)n * Kpad + k] = (__bf16)r;
}

// ---- MFMA GEMM: C[M x 128] = A[M x K] @ W[K x 128], bf16x3 split ----------
// 256 thr = 4 waves (2x2), tile 128x128, BK=32, 16x16x32 MFMA
template<bool BIAS, bool RELU, bool AL4>
__global__ __launch_bounds__(256)
void gemm_mfma(const float* __restrict__ A, const __bf16* __restrict__ wh,
               const __bf16* __restrict__ wl, const float* __restrict__ bias,
               float* __restrict__ C, int M, int K, int Kpad) {
  __shared__ __bf16 ah[128 * 40];   // stride 40 (80B): 5r%8 bank-quad spread
  __shared__ __bf16 al[128 * 40];
  __shared__ __bf16 bh[128 * 40];
  __shared__ __bf16 bl[128 * 40];
  const int t = threadIdx.x;
  const int row0 = blockIdx.x * 128;
  const int wave = t >> 6, lane = t & 63;
  const int wr = wave >> 1, wc = wave & 1;   // wave -> 64x64 quadrant
  const int lr = lane & 15, kg = lane >> 4;  // frag row/col, k-group

  f32x4 acc[4][4] = {};

  const int ar = t >> 1, akh = t & 1;        // A staging: row, k-half
  const long arow = row0 + ar;
  const bool rok = (arow < M);

  for (int k0 = 0; k0 < Kpad; k0 += 32) {
    // ---- stage A: fp32 -> (hi, lo) bf16 ----
    {
      const float* ap = A + arow * (long)K + k0 + akh * 16;
      float fv[16];
      if (AL4) {
#pragma unroll
        for (int q = 0; q < 4; ++q) {
          f32x4 v4 = rok ? *(const f32x4*)(ap + q * 4) : (f32x4){0.f, 0.f, 0.f, 0.f};
          fv[q * 4 + 0] = v4.x; fv[q * 4 + 1] = v4.y;
          fv[q * 4 + 2] = v4.z; fv[q * 4 + 3] = v4.w;
        }
      } else {
#pragma unroll
        for (int j = 0; j < 16; ++j) {
          int gk = k0 + akh * 16 + j;
          fv[j] = (rok && gk < K) ? ap[j] : 0.f;
        }
      }
      bf16x8 h0, h1, l0, l1;
#pragma unroll
      for (int j = 0; j < 8; ++j) {
        __bf16 h = (__bf16)fv[j];
        h0[j] = h; l0[j] = (__bf16)(fv[j] - (float)h);
      }
#pragma unroll
      for (int j = 0; j < 8; ++j) {
        __bf16 h = (__bf16)fv[8 + j];
        h1[j] = h; l1[j] = (__bf16)(fv[8 + j] - (float)h);
      }
      __bf16* dh = &ah[ar * 40 + akh * 16];
      __bf16* dl = &al[ar * 40 + akh * 16];
      *(bf16x8*)(dh) = h0; *(bf16x8*)(dh + 8) = h1;
      *(bf16x8*)(dl) = l0; *(bf16x8*)(dl + 8) = l1;
    }
    // ---- stage B: copy pre-split W^T tiles ----
#pragma unroll
    for (int i = 0; i < 4; ++i) {
      int idx = t + i * 256;            // 1024 x 16B
      int plane = idx >> 9;
      int r = (idx >> 2) & 127;
      int kq = idx & 3;
      const __bf16* srcw = plane ? wl : wh;
      bf16x8 v = *(const bf16x8*)&srcw[(long)r * Kpad + k0 + kq * 8];
      __bf16* d = plane ? bl : bh;
      *(bf16x8*)&d[r * 40 + kq * 8] = v;
    }
    __syncthreads();
    // ---- fragments ----
    bf16x8 fa_h[4], fa_l[4], fb_h[4], fb_l[4];
#pragma unroll
    for (int mi = 0; mi < 4; ++mi) {
      int r = wr * 64 + mi * 16 + lr;
      fa_h[mi] = *(const bf16x8*)&ah[r * 40 + kg * 8];
      fa_l[mi] = *(const bf16x8*)&al[r * 40 + kg * 8];
    }
#pragma unroll
    for (int ni = 0; ni < 4; ++ni) {
      int c = wc * 64 + ni * 16 + lr;
      fb_h[ni] = *(const bf16x8*)&bh[c * 40 + kg * 8];
      fb_l[ni] = *(const bf16x8*)&bl[c * 40 + kg * 8];
    }
#pragma unroll
    for (int mi = 0; mi < 4; ++mi)
#pragma unroll
      for (int ni = 0; ni < 4; ++ni) {
        mfma_bf16(acc[mi][ni], fa_h[mi], fb_h[ni]);
        mfma_bf16(acc[mi][ni], fa_l[mi], fb_h[ni]);
        mfma_bf16(acc[mi][ni], fa_h[mi], fb_l[ni]);
      }
    __syncthreads();
  }
  // ---- epilogue: C/D layout col=lane&15, row=(lane>>4)*4+reg ----
#pragma unroll
  for (int mi = 0; mi < 4; ++mi) {
#pragma unroll
    for (int ni = 0; ni < 4; ++ni) {
      int col = wc * 64 + ni * 16 + lr;
      float bv = BIAS ? bias[col] : 0.f;
#pragma unroll
      for (int r = 0; r < 4; ++r) {
        int row = row0 + wr * 64 + mi * 16 + kg * 4 + r;
        if (row < M) {
          float v = acc[mi][ni][r] + bv;
          if (RELU) v = fmaxf(v, 0.f);
          C[(long)row * 128 + col] = v;
        }
      }
    }
  }
}

// ---------------- CSR build -------------------------------------------------
__global__ __launch_bounds__(256)
void deg_count(const int* __restrict__ dst, int* __restrict__ deg, int E) {
  int e = blockIdx.x * 256 + threadIdx.x;
  if (e < E) atomicAdd(&deg[dst[e]], 1);
}

__global__ __launch_bounds__(256)
void scan_sums(const int* __restrict__ deg, int* __restrict__ bsum) {
  __shared__ int sm[256];
  int base = blockIdx.x * SCAN_CHUNK + threadIdx.x * SCAN_E;
  int s = 0;
#pragma unroll
  for (int k = 0; k < SCAN_E; ++k) { int i = base + k; if (i < NN) s += deg[i]; }
  sm[threadIdx.x] = s; __syncthreads();
  for (int off = 128; off > 0; off >>= 1) {
    if (threadIdx.x < off) sm[threadIdx.x] += sm[threadIdx.x + off];
    __syncthreads();
  }
  if (threadIdx.x == 0) bsum[blockIdx.x] = sm[0];
}

__global__ void scan_offs(const int* __restrict__ bsum, int* __restrict__ boff,
                          int* __restrict__ rowptr) {
  if (threadIdx.x == 0) {
    int run = 0;
    for (int i = 0; i < SCAN_NB; ++i) { boff[i] = run; run += bsum[i]; }
    rowptr[NN] = run;
  }
}

__global__ __launch_bounds__(256)
void scan_final(const int* __restrict__ boff, int* __restrict__ rowptr,
                int* __restrict__ cursor) {
  __shared__ int sm[256];
  int t = threadIdx.x;
  int base = blockIdx.x * SCAN_CHUNK + t * SCAN_E;
  int v[SCAN_E]; int s = 0;
#pragma unroll
  for (int k = 0; k < SCAN_E; ++k) { int i = base + k; v[k] = (i < NN) ? rowptr[i] : 0; s += v[k]; }
  sm[t] = s; __syncthreads();
  for (int off = 1; off < 256; off <<= 1) {
    int val = sm[t]; int add = (t >= off) ? sm[t - off] : 0;
    __syncthreads();
    sm[t] = val + add;
    __syncthreads();
  }
  int excl = (t == 0 ? 0 : sm[t - 1]) + boff[blockIdx.x];
#pragma unroll
  for (int k = 0; k < SCAN_E; ++k) {
    int i = base + k;
    if (i < NN) { rowptr[i] = excl; cursor[i] = excl; }
    excl += v[k];
  }
}

__global__ __launch_bounds__(256)
void scatter_csr(const int* __restrict__ src, const int* __restrict__ dst,
                 int* __restrict__ cursor, int* __restrict__ csr_src, int E) {
  int e = blockIdx.x * 256 + threadIdx.x;
  if (e < E) {
    int d = dst[e];
    int pos = atomicAdd(&cursor[d], 1);
    csr_src[pos] = src[e];
  }
}

// ---------------- fold BN params --------------------------------------------
__global__ void bn_prep(const float* __restrict__ b1, const float* __restrict__ g,
                        const float* __restrict__ bb, const float* __restrict__ m,
                        const float* __restrict__ v, float* __restrict__ scale,
                        float* __restrict__ shift) {
  int c = threadIdx.x;
  float s = g[c] * rsqrtf(v[c] + BN_EPS);
  scale[c] = s;
  shift[c] = (b1[c] - m[c]) * s + bb[c];
}

// ------- gather+sum over in-edges, fused BN+ReLU ---------------------------
__global__ __launch_bounds__(256)
void gather_bn(const float* __restrict__ y, const int* __restrict__ rowptr,
               const int* __restrict__ csr_src, const float* __restrict__ scale,
               const float* __restrict__ shift, float* __restrict__ out) {
  const int grp = threadIdx.x >> 5;
  const int lane = threadIdx.x & 31;
  const int node = blockIdx.x * 8 + grp;
  if (node >= NN) return;
  const float4* y4 = (const float4*)y;
  int s = rowptr[node], e = rowptr[node + 1];
  float4 acc = y4[(long)node * 32 + lane];
  for (int i = s; i < e; ++i) {
    int sn = csr_src[i];
    float4 v = y4[(long)sn * 32 + lane];
    acc.x += v.x; acc.y += v.y; acc.z += v.z; acc.w += v.w;
  }
  float4 sc = ((const float4*)scale)[lane];
  float4 sh = ((const float4*)shift)[lane];
  float4 o;
  o.x = fmaxf(acc.x * sc.x + sh.x, 0.f);
  o.y = fmaxf(acc.y * sc.y + sh.y, 0.f);
  o.z = fmaxf(acc.z * sc.z + sh.z, 0.f);
  o.w = fmaxf(acc.w * sc.w + sh.w, 0.f);
  ((float4*)out)[(long)node * 32 + lane] = o;
}

// ---------------- graph boundaries / pooling / head ------------------------
__global__ void graph_bounds(const int* __restrict__ batch, int* __restrict__ gstart, int n) {
  int g = blockIdx.x * 64 + threadIdx.x;
  if (g > NG) return;
  int lo = 0, hi = n;
  while (lo < hi) {
    int mid = (lo + hi) >> 1;
    if (batch[mid] < g) lo = mid + 1; else hi = mid;
  }
  gstart[g] = lo;
}

__global__ __launch_bounds__(128)
void pool_mean(const float* __restrict__ h, const int* __restrict__ gstart,
               float* __restrict__ pooled, int layer) {
  int g = blockIdx.x, c = threadIdx.x;
  int s = gstart[g], e = gstart[g + 1];
  float acc = 0.f;
  for (int i = s; i < e; ++i) acc += h[(long)i * 128 + c];
  pooled[g * 384 + layer * 128 + c] = acc / fmaxf((float)(e - s), 1.f);
}

__global__ __launch_bounds__(384)
void lin1_k(const float* __restrict__ pooled, const float* __restrict__ w,
            const float* __restrict__ b, float* __restrict__ z) {
  __shared__ float pr[384];
  int mrow = blockIdx.x, t = threadIdx.x;
  pr[t] = pooled[mrow * 384 + t];
  __syncthreads();
  float acc = b[t];
  for (int k = 0; k < 384; ++k) acc += pr[k] * w[k * 384 + t];
  z[mrow * 384 + t] = fmaxf(acc, 0.f);
}

__global__ __launch_bounds__(192)
void lin2_k(const float* __restrict__ z, const float* __restrict__ w,
            const float* __restrict__ b, float* __restrict__ out) {
  int idx = blockIdx.x * 192 + threadIdx.x;
  if (idx >= NG * 3) return;
  int mrow = idx / 3, j = idx % 3;
  float acc = b[j];
  for (int k = 0; k < 384; ++k) acc += z[mrow * 384 + k] * w[k * 3 + j];
  out[idx] = acc;
}

extern "C" void kernel_launch(void* const* d_in, const int* in_sizes, int n_in,
                              void* d_out, int out_size, void* d_ws, size_t ws_size,
                              hipStream_t stream) {
  const float* x = (const float*)d_in[0];
  const int* ei = (const int*)d_in[1];
  const int* batch = (const int*)d_in[2];
  const int* srcv = ei;
  const int* dstv = ei + NE;
  const float* cw1[3] = {(const float*)d_in[3], (const float*)d_in[11], (const float*)d_in[19]};
  const float* cb1[3] = {(const float*)d_in[4], (const float*)d_in[12], (const float*)d_in[20]};
  const float* cg[3]  = {(const float*)d_in[5], (const float*)d_in[13], (const float*)d_in[21]};
  const float* cbb[3] = {(const float*)d_in[6], (const float*)d_in[14], (const float*)d_in[22]};
  const float* cm[3]  = {(const float*)d_in[7], (const float*)d_in[15], (const float*)d_in[23]};
  const float* cv[3]  = {(const float*)d_in[8], (const float*)d_in[16], (const float*)d_in[24]};
  const float* cw2[3] = {(const float*)d_in[9], (const float*)d_in[17], (const float*)d_in[25]};
  const float* cb2[3] = {(const float*)d_in[10], (const float*)d_in[18], (const float*)d_in[26]};
  const float* lin1_w = (const float*)d_in[27];
  const float* lin1_b = (const float*)d_in[28];
  const float* lin2_w = (const float*)d_in[29];
  const float* lin2_b = (const float*)d_in[30];

  const size_t NNF = (size_t)NN * 128;
  float* wsf = (float*)d_ws;
  float* y    = wsf;               // NN*128
  float* hpre = y + NNF;           // NN*128
  float* h0   = hpre + NNF;
  float* h1   = h0 + NNF;
  float* h2   = y;                 // alias
  float* hbuf[3] = {h0, h1, h2};
  float* pooled = hpre;            // alias
  float* z = pooled + (size_t)NG * 384;
  int* rowptr  = (int*)(h1 + NNF); // NN+1
  int* cursor  = rowptr + NN + 1;  // NN
  int* csr_src = cursor + NN;      // NE
  int* bsum    = csr_src + NE;
  int* boff    = bsum + 32;
  int* gstart  = boff + 64;        // 257
  float* scale = (float*)(gstart + 260);
  float* shift = scale + 128;
  __bf16* wth  = (__bf16*)(shift + 128);        // 128*544
  __bf16* wtl  = wth + (size_t)128 * 544;

  // ---- build CSR (by dst) once ----
  hipMemsetAsync(rowptr, 0, (NN + 1) * sizeof(int), stream);
  deg_count<<<(NE + 255) / 256, 256, 0, stream>>>(dstv, rowptr, NE);
  scan_sums<<<SCAN_NB, 256, 0, stream>>>(rowptr, bsum);
  scan_offs<<<1, 64, 0, stream>>>(bsum, boff, rowptr);
  scan_final<<<SCAN_NB, 256, 0, stream>>>(boff, rowptr, cursor);
  scatter_csr<<<(NE + 255) / 256, 256, 0, stream>>>(srcv, dstv, cursor, csr_src, NE);

  const int gemm_grid = (NN + 127) / 128;
  for (int c = 0; c < 3; ++c) {
    const float* in = (c == 0) ? x : hbuf[c - 1];
    int K = (c == 0) ? 513 : 128;
    int Kpad = (c == 0) ? 544 : 128;
    bn_prep<<<1, 128, 0, stream>>>(cb1[c], cg[c], cbb[c], cm[c], cv[c], scale, shift);
    wprep<<<(128 * Kpad + 255) / 256, 256, 0, stream>>>(cw1[c], wth, wtl, K, Kpad);
    if (c == 0)
      gemm_mfma<false, false, false><<<gemm_grid, 256, 0, stream>>>(in, wth, wtl, nullptr, y, NN, K, Kpad);
    else
      gemm_mfma<false, false, true><<<gemm_grid, 256, 0, stream>>>(in, wth, wtl, nullptr, y, NN, K, Kpad);
    gather_bn<<<(NN + 7) / 8, 256, 0, stream>>>(y, rowptr, csr_src, scale, shift, hpre);
    wprep<<<(128 * 128 + 255) / 256, 256, 0, stream>>>(cw2[c], wth, wtl, 128, 128);
    gemm_mfma<true, true, true><<<gemm_grid, 256, 0, stream>>>(hpre, wth, wtl, cb2[c], hbuf[c], NN, 128, 128);
  }
  graph_bounds<<<5, 64, 0, stream>>>(batch, gstart, NN);
  for (int l = 0; l < 3; ++l)
    pool_mean<<<NG, 128, 0, stream>>>(hbuf[l], gstart, pooled, l);
  lin1_k<<<NG, 384, 0, stream>>>(pooled, lin1_w, lin1_b, z);
  lin2_k<<<4, 192, 0, stream>>>(z, lin2_w, lin2_b, (float*)d_out);
}

// Round 4
// 402.950 us; speedup vs baseline: 7.0412x; 1.3474x over previous
//
#include <hip/hip_runtime.h>

#define NN 50000
#define NE 400000
#define NG 256
#define BN_EPS 1e-5f
#define SCAN_E 8
#define SCAN_CHUNK 2048           // 256 threads * 8
#define SCAN_NB 25                // ceil(50000/2048)

typedef __attribute__((ext_vector_type(4))) float f32x4;
typedef __bf16 bf16x8 __attribute__((ext_vector_type(8)));
typedef __bf16 bf16x4 __attribute__((ext_vector_type(4)));

__device__ __forceinline__ void mfma_bf16(f32x4& d, bf16x8 a, bf16x8 b) {
  asm volatile("v_mfma_f32_16x16x32_bf16 %0, %1, %2, %0" : "+v"(d) : "v"(a), "v"(b));
}

// ---- x pre-split: fp32 [NN][513] -> bf16 hi/lo planes [NN][544], zero-pad --
__global__ __launch_bounds__(256)
void xsplit(const float* __restrict__ x, __bf16* __restrict__ xh,
            __bf16* __restrict__ xl) {
  long idx = (long)blockIdx.x * 256 + threadIdx.x;   // over NN*544
  if (idx >= (long)NN * 544) return;
  int r = (int)(idx / 544), k = (int)(idx % 544);
  float v = (k < 513) ? x[(long)r * 513 + k] : 0.f;
  __bf16 h = (__bf16)v;
  xh[idx] = h;
  xl[idx] = (__bf16)(v - (float)h);
}

// ---- W pre-split: wh/wl[n][k] = bf16 hi/lo of W[k][n], zero-padded to Kpad --
__global__ __launch_bounds__(256)
void wprep(const float* __restrict__ W, __bf16* __restrict__ wh,
           __bf16* __restrict__ wl, int K, int Kpad) {
  int idx = blockIdx.x * 256 + threadIdx.x;
  if (idx >= 128 * Kpad) return;
  int n = idx & 127, k = idx >> 7;
  float v = (k < K) ? W[(long)k * 128 + n] : 0.f;
  __bf16 h = (__bf16)v;
  wh[(long)n * Kpad + k] = h;
  wl[(long)n * Kpad + k] = (__bf16)(v - (float)h);
}

// ---- MFMA GEMM on pre-split bf16: C[M x 128] = A[M x Kpad] @ W[Kpad x 128] -
// 512 thr = 8 waves (2x4), tile 64x128, each wave 32x32, BK=32
template<bool BIAS, bool RELU, bool OUT_SPLIT>
__global__ __launch_bounds__(512)
void gemm_bsp(const __bf16* __restrict__ Ah, const __bf16* __restrict__ Al,
              const __bf16* __restrict__ Wh, const __bf16* __restrict__ Wl,
              const float* __restrict__ bias, float* __restrict__ Cf,
              __bf16* __restrict__ Ch, __bf16* __restrict__ Cl,
              int M, int Kpad) {
  __shared__ __align__(16) __bf16 ah[64 * 40];
  __shared__ __align__(16) __bf16 al[64 * 40];
  __shared__ __align__(16) __bf16 bh[128 * 40];
  __shared__ __align__(16) __bf16 bl[128 * 40];
  const int t = threadIdx.x;
  const int row0 = blockIdx.x * 64;
  const int wave = t >> 6, lane = t & 63;
  const int wr = wave >> 2, wc = wave & 3;   // 2x4 wave grid -> 32x32 tiles
  const int lr = lane & 15, kg = lane >> 4;

  // A staging: 512 chunks = 2 planes x 64 rows x 4 k-octs, 1 per thread
  const int a_pl = t >> 8, a_r = (t >> 2) & 63, a_ko = t & 3;
  const bool a_ok = (row0 + a_r) < M;
  const __bf16* a_src = (a_pl ? Al : Ah) + (long)(row0 + a_r) * Kpad + a_ko * 8;
  __bf16* a_dst = (a_pl ? al : ah) + a_r * 40 + a_ko * 8;
  // B staging: 128 rows x 4 k-octs, both planes per thread
  const int b_r = (t >> 2) & 127, b_ko = t & 3;
  const __bf16* bh_src = Wh + (long)b_r * Kpad + b_ko * 8;
  const __bf16* bl_src = Wl + (long)b_r * Kpad + b_ko * 8;
  __bf16* bh_dst = bh + b_r * 40 + b_ko * 8;
  __bf16* bl_dst = bl + b_r * 40 + b_ko * 8;

  f32x4 acc[2][2] = {};
  bf16x8 zero8;
#pragma unroll
  for (int j = 0; j < 8; ++j) zero8[j] = (__bf16)0.f;

  bf16x8 av = a_ok ? *(const bf16x8*)a_src : zero8;
  bf16x8 bv0 = *(const bf16x8*)bh_src;
  bf16x8 bv1 = *(const bf16x8*)bl_src;

  for (int k0 = 0; k0 < Kpad; k0 += 32) {
    __syncthreads();
    *(bf16x8*)a_dst = av;
    *(bf16x8*)bh_dst = bv0;
    *(bf16x8*)bl_dst = bv1;
    __syncthreads();
    int k1 = k0 + 32;
    if (k1 < Kpad) {            // prefetch next tile; overlaps MFMA below
      av = a_ok ? *(const bf16x8*)(a_src + k1) : zero8;
      bv0 = *(const bf16x8*)(bh_src + k1);
      bv1 = *(const bf16x8*)(bl_src + k1);
    }
    bf16x8 fah[2], fal[2], fbh[2], fbl[2];
#pragma unroll
    for (int mi = 0; mi < 2; ++mi) {
      int r = wr * 32 + mi * 16 + lr;
      fah[mi] = *(const bf16x8*)&ah[r * 40 + kg * 8];
      fal[mi] = *(const bf16x8*)&al[r * 40 + kg * 8];
    }
#pragma unroll
    for (int ni = 0; ni < 2; ++ni) {
      int c = wc * 32 + ni * 16 + lr;
      fbh[ni] = *(const bf16x8*)&bh[c * 40 + kg * 8];
      fbl[ni] = *(const bf16x8*)&bl[c * 40 + kg * 8];
    }
#pragma unroll
    for (int mi = 0; mi < 2; ++mi)
#pragma unroll
      for (int ni = 0; ni < 2; ++ni) {
        mfma_bf16(acc[mi][ni], fah[mi], fbh[ni]);
        mfma_bf16(acc[mi][ni], fal[mi], fbh[ni]);
        mfma_bf16(acc[mi][ni], fah[mi], fbl[ni]);
      }
  }
  // epilogue: C/D layout col=lane&15, row=(lane>>4)*4+reg
#pragma unroll
  for (int mi = 0; mi < 2; ++mi) {
#pragma unroll
    for (int ni = 0; ni < 2; ++ni) {
      int col = wc * 32 + ni * 16 + lr;
      float bv = BIAS ? bias[col] : 0.f;
#pragma unroll
      for (int r = 0; r < 4; ++r) {
        int row = row0 + wr * 32 + mi * 16 + kg * 4 + r;
        if (row < M) {
          float v = acc[mi][ni][r] + bv;
          if (RELU) v = fmaxf(v, 0.f);
          if (OUT_SPLIT) {
            __bf16 h = (__bf16)v;
            Ch[(long)row * 128 + col] = h;
            Cl[(long)row * 128 + col] = (__bf16)(v - (float)h);
          } else {
            Cf[(long)row * 128 + col] = v;
          }
        }
      }
    }
  }
}

// ---------------- CSR build -------------------------------------------------
__global__ __launch_bounds__(256)
void deg_count(const int* __restrict__ dst, int* __restrict__ deg, int E) {
  int e = blockIdx.x * 256 + threadIdx.x;
  if (e < E) atomicAdd(&deg[dst[e]], 1);
}

__global__ __launch_bounds__(256)
void scan_sums(const int* __restrict__ deg, int* __restrict__ bsum) {
  __shared__ int sm[256];
  int base = blockIdx.x * SCAN_CHUNK + threadIdx.x * SCAN_E;
  int s = 0;
#pragma unroll
  for (int k = 0; k < SCAN_E; ++k) { int i = base + k; if (i < NN) s += deg[i]; }
  sm[threadIdx.x] = s; __syncthreads();
  for (int off = 128; off > 0; off >>= 1) {
    if (threadIdx.x < off) sm[threadIdx.x] += sm[threadIdx.x + off];
    __syncthreads();
  }
  if (threadIdx.x == 0) bsum[blockIdx.x] = sm[0];
}

__global__ void scan_offs(const int* __restrict__ bsum, int* __restrict__ boff,
                          int* __restrict__ rowptr) {
  if (threadIdx.x == 0) {
    int run = 0;
    for (int i = 0; i < SCAN_NB; ++i) { boff[i] = run; run += bsum[i]; }
    rowptr[NN] = run;
  }
}

__global__ __launch_bounds__(256)
void scan_final(const int* __restrict__ boff, int* __restrict__ rowptr,
                int* __restrict__ cursor) {
  __shared__ int sm[256];
  int t = threadIdx.x;
  int base = blockIdx.x * SCAN_CHUNK + t * SCAN_E;
  int v[SCAN_E]; int s = 0;
#pragma unroll
  for (int k = 0; k < SCAN_E; ++k) { int i = base + k; v[k] = (i < NN) ? rowptr[i] : 0; s += v[k]; }
  sm[t] = s; __syncthreads();
  for (int off = 1; off < 256; off <<= 1) {
    int val = sm[t]; int add = (t >= off) ? sm[t - off] : 0;
    __syncthreads();
    sm[t] = val + add;
    __syncthreads();
  }
  int excl = (t == 0 ? 0 : sm[t - 1]) + boff[blockIdx.x];
#pragma unroll
  for (int k = 0; k < SCAN_E; ++k) {
    int i = base + k;
    if (i < NN) { rowptr[i] = excl; cursor[i] = excl; }
    excl += v[k];
  }
}

__global__ __launch_bounds__(256)
void scatter_csr(const int* __restrict__ src, const int* __restrict__ dst,
                 int* __restrict__ cursor, int* __restrict__ csr_src, int E) {
  int e = blockIdx.x * 256 + threadIdx.x;
  if (e < E) {
    int d = dst[e];
    int pos = atomicAdd(&cursor[d], 1);
    csr_src[pos] = src[e];
  }
}

// ---------------- fold BN params --------------------------------------------
__global__ void bn_prep(const float* __restrict__ b1, const float* __restrict__ g,
                        const float* __restrict__ bb, const float* __restrict__ m,
                        const float* __restrict__ v, float* __restrict__ scale,
                        float* __restrict__ shift) {
  int c = threadIdx.x;
  float s = g[c] * rsqrtf(v[c] + BN_EPS);
  scale[c] = s;
  shift[c] = (b1[c] - m[c]) * s + bb[c];
}

// ------- gather+sum over in-edges, fused BN+ReLU, emit split bf16 ----------
__global__ __launch_bounds__(256)
void gather_bn_split(const float* __restrict__ y, const int* __restrict__ rowptr,
                     const int* __restrict__ csr_src, const float* __restrict__ scale,
                     const float* __restrict__ shift, __bf16* __restrict__ oh,
                     __bf16* __restrict__ ol) {
  const int grp = threadIdx.x >> 5;
  const int lane = threadIdx.x & 31;
  const int node = blockIdx.x * 8 + grp;
  if (node >= NN) return;
  const float4* y4 = (const float4*)y;
  int s = rowptr[node], e = rowptr[node + 1];
  float4 acc = y4[(long)node * 32 + lane];
  float4 acc2 = {0.f, 0.f, 0.f, 0.f};
  int i = s;
  for (; i + 3 < e; i += 4) {
    int s0 = csr_src[i], s1 = csr_src[i + 1], s2 = csr_src[i + 2], s3 = csr_src[i + 3];
    float4 v0 = y4[(long)s0 * 32 + lane];
    float4 v1 = y4[(long)s1 * 32 + lane];
    float4 v2 = y4[(long)s2 * 32 + lane];
    float4 v3 = y4[(long)s3 * 32 + lane];
    acc.x += v0.x; acc.y += v0.y; acc.z += v0.z; acc.w += v0.w;
    acc2.x += v1.x; acc2.y += v1.y; acc2.z += v1.z; acc2.w += v1.w;
    acc.x += v2.x; acc.y += v2.y; acc.z += v2.z; acc.w += v2.w;
    acc2.x += v3.x; acc2.y += v3.y; acc2.z += v3.z; acc2.w += v3.w;
  }
  for (; i < e; ++i) {
    int sn = csr_src[i];
    float4 v = y4[(long)sn * 32 + lane];
    acc.x += v.x; acc.y += v.y; acc.z += v.z; acc.w += v.w;
  }
  acc.x += acc2.x; acc.y += acc2.y; acc.z += acc2.z; acc.w += acc2.w;
  float4 sc = ((const float4*)scale)[lane];
  float4 sh = ((const float4*)shift)[lane];
  float o0 = fmaxf(acc.x * sc.x + sh.x, 0.f);
  float o1 = fmaxf(acc.y * sc.y + sh.y, 0.f);
  float o2 = fmaxf(acc.z * sc.z + sh.z, 0.f);
  float o3 = fmaxf(acc.w * sc.w + sh.w, 0.f);
  __bf16 h0 = (__bf16)o0, h1 = (__bf16)o1, h2 = (__bf16)o2, h3 = (__bf16)o3;
  bf16x4 hv, lv;
  hv[0] = h0; hv[1] = h1; hv[2] = h2; hv[3] = h3;
  lv[0] = (__bf16)(o0 - (float)h0); lv[1] = (__bf16)(o1 - (float)h1);
  lv[2] = (__bf16)(o2 - (float)h2); lv[3] = (__bf16)(o3 - (float)h3);
  *(bf16x4*)&oh[(long)node * 128 + lane * 4] = hv;
  *(bf16x4*)&ol[(long)node * 128 + lane * 4] = lv;
}

// ---------------- graph boundaries / pooling / head ------------------------
__global__ void graph_bounds(const int* __restrict__ batch, int* __restrict__ gstart, int n) {
  int g = blockIdx.x * 64 + threadIdx.x;
  if (g > NG) return;
  int lo = 0, hi = n;
  while (lo < hi) {
    int mid = (lo + hi) >> 1;
    if (batch[mid] < g) lo = mid + 1; else hi = mid;
  }
  gstart[g] = lo;
}

// pooled from split planes; grid (NG, 3)
__global__ __launch_bounds__(128)
void pool_mean_split(const __bf16* __restrict__ h0h, const __bf16* __restrict__ h0l,
                     const __bf16* __restrict__ h1h, const __bf16* __restrict__ h1l,
                     const __bf16* __restrict__ h2h, const __bf16* __restrict__ h2l,
                     const int* __restrict__ gstart, float* __restrict__ pooled) {
  int layer = blockIdx.y;
  const __bf16* hh = (layer == 0) ? h0h : (layer == 1) ? h1h : h2h;
  const __bf16* hl = (layer == 0) ? h0l : (layer == 1) ? h1l : h2l;
  int g = blockIdx.x, c = threadIdx.x;
  int s = gstart[g], e = gstart[g + 1];
  float a0 = 0.f, a1 = 0.f, a2 = 0.f, a3 = 0.f;
  int i = s;
  for (; i + 3 < e; i += 4) {
    a0 += (float)hh[(long)i * 128 + c] + (float)hl[(long)i * 128 + c];
    a1 += (float)hh[(long)(i + 1) * 128 + c] + (float)hl[(long)(i + 1) * 128 + c];
    a2 += (float)hh[(long)(i + 2) * 128 + c] + (float)hl[(long)(i + 2) * 128 + c];
    a3 += (float)hh[(long)(i + 3) * 128 + c] + (float)hl[(long)(i + 3) * 128 + c];
  }
  for (; i < e; ++i)
    a0 += (float)hh[(long)i * 128 + c] + (float)hl[(long)i * 128 + c];
  float acc = (a0 + a1) + (a2 + a3);
  pooled[g * 384 + layer * 128 + c] = acc / fmaxf((float)(e - s), 1.f);
}

__global__ __launch_bounds__(384)
void lin1_k(const float* __restrict__ pooled, const float* __restrict__ w,
            const float* __restrict__ b, float* __restrict__ z) {
  __shared__ float pr[384];
  int mrow = blockIdx.x, t = threadIdx.x;
  pr[t] = pooled[mrow * 384 + t];
  __syncthreads();
  float acc = b[t];
  for (int k = 0; k < 384; ++k) acc += pr[k] * w[k * 384 + t];
  z[mrow * 384 + t] = fmaxf(acc, 0.f);
}

__global__ __launch_bounds__(192)
void lin2_k(const float* __restrict__ z, const float* __restrict__ w,
            const float* __restrict__ b, float* __restrict__ out) {
  int idx = blockIdx.x * 192 + threadIdx.x;
  if (idx >= NG * 3) return;
  int mrow = idx / 3, j = idx % 3;
  float acc = b[j];
  for (int k = 0; k < 384; ++k) acc += z[mrow * 384 + k] * w[k * 3 + j];
  out[idx] = acc;
}

extern "C" void kernel_launch(void* const* d_in, const int* in_sizes, int n_in,
                              void* d_out, int out_size, void* d_ws, size_t ws_size,
                              hipStream_t stream) {
  const float* x = (const float*)d_in[0];
  const int* ei = (const int*)d_in[1];
  const int* batch = (const int*)d_in[2];
  const int* srcv = ei;
  const int* dstv = ei + NE;
  const float* cw1[3] = {(const float*)d_in[3], (const float*)d_in[11], (const float*)d_in[19]};
  const float* cb1[3] = {(const float*)d_in[4], (const float*)d_in[12], (const float*)d_in[20]};
  const float* cg[3]  = {(const float*)d_in[5], (const float*)d_in[13], (const float*)d_in[21]};
  const float* cbb[3] = {(const float*)d_in[6], (const float*)d_in[14], (const float*)d_in[22]};
  const float* cm[3]  = {(const float*)d_in[7], (const float*)d_in[15], (const float*)d_in[23]};
  const float* cv[3]  = {(const float*)d_in[8], (const float*)d_in[16], (const float*)d_in[24]};
  const float* cw2[3] = {(const float*)d_in[9], (const float*)d_in[17], (const float*)d_in[25]};
  const float* cb2[3] = {(const float*)d_in[10], (const float*)d_in[18], (const float*)d_in[26]};
  const float* lin1_w = (const float*)d_in[27];
  const float* lin1_b = (const float*)d_in[28];
  const float* lin2_w = (const float*)d_in[29];
  const float* lin2_b = (const float*)d_in[30];

  const size_t NNF = (size_t)NN * 128;        // 6.4M
  float* wsf = (float*)d_ws;
  float* y = wsf;                              // [0, 6.4M) f32
  __bf16* Xb = (__bf16*)(wsf + NNF);           // 54.4M bf16 region (108.8 MB)
  // x planes (dead after conv1 gemm1):
  __bf16* xh = Xb;                             // [0, 27.2M) bf16
  __bf16* xl = Xb + (size_t)27200000;          // [27.2M, 54.4M)
  // aliased after x is consumed:
  __bf16* gh = Xb;                             // gather split out, 6.4M
  __bf16* gl = Xb + (size_t)6400000;
  __bf16* hh[3], *hl[3];
  for (int c = 0; c < 3; ++c) {
    hh[c] = Xb + (size_t)12800000 + (size_t)c * 12800000;
    hl[c] = hh[c] + (size_t)6400000;
  }
  float* misc = wsf + NNF + (size_t)27200000;  // after X region
  float* pooled = misc;                        // 256*384
  float* z      = pooled + (size_t)NG * 384;
  float* scale  = z + (size_t)NG * 384;        // 128
  float* shift  = scale + 128;
  __bf16* wth   = (__bf16*)(shift + 128);      // 128*544 bf16
  __bf16* wtl   = wth + (size_t)128 * 544;
  int* rowptr   = (int*)(wtl + (size_t)128 * 544);  // NN+1
  int* cursor   = rowptr + NN + 1;
  int* csr_src  = cursor + NN;
  int* bsum     = csr_src + NE;
  int* boff     = bsum + 32;
  int* gstart   = boff + 64;                   // 257

  // ---- build CSR (by dst) once ----
  hipMemsetAsync(rowptr, 0, (NN + 1) * sizeof(int), stream);
  deg_count<<<(NE + 255) / 256, 256, 0, stream>>>(dstv, rowptr, NE);
  scan_sums<<<SCAN_NB, 256, 0, stream>>>(rowptr, bsum);
  scan_offs<<<1, 64, 0, stream>>>(bsum, boff, rowptr);
  scan_final<<<SCAN_NB, 256, 0, stream>>>(boff, rowptr, cursor);
  scatter_csr<<<(NE + 255) / 256, 256, 0, stream>>>(srcv, dstv, cursor, csr_src, NE);

  // ---- pre-split x ----
  xsplit<<<(int)(((long)NN * 544 + 255) / 256), 256, 0, stream>>>(x, xh, xl);

  const int gemm_grid = (NN + 63) / 64;        // 782
  for (int c = 0; c < 3; ++c) {
    int K = (c == 0) ? 513 : 128;
    int Kpad = (c == 0) ? 544 : 128;
    const __bf16* Ah = (c == 0) ? xh : hh[c - 1];
    const __bf16* Al = (c == 0) ? xl : hl[c - 1];
    bn_prep<<<1, 128, 0, stream>>>(cb1[c], cg[c], cbb[c], cm[c], cv[c], scale, shift);
    wprep<<<(128 * Kpad + 255) / 256, 256, 0, stream>>>(cw1[c], wth, wtl, K, Kpad);
    gemm_bsp<false, false, false><<<gemm_grid, 512, 0, stream>>>(
        Ah, Al, wth, wtl, nullptr, y, nullptr, nullptr, NN, Kpad);
    gather_bn_split<<<(NN + 7) / 8, 256, 0, stream>>>(y, rowptr, csr_src, scale, shift, gh, gl);
    wprep<<<(128 * 128 + 255) / 256, 256, 0, stream>>>(cw2[c], wth, wtl, 128, 128);
    gemm_bsp<true, true, true><<<gemm_grid, 512, 0, stream>>>(
        gh, gl, wth, wtl, cb2[c], nullptr, hh[c], hl[c], NN, 128);
  }
  graph_bounds<<<5, 64, 0, stream>>>(batch, gstart, NN);
  pool_mean_split<<<dim3(NG, 3), 128, 0, stream>>>(hh[0], hl[0], hh[1], hl[1], hh[2], hl[2],
                                                   gstart, pooled);
  lin1_k<<<NG, 384, 0, stream>>>(pooled, lin1_w, lin1_b, z);
  lin2_k<<<4, 192, 0, stream>>>(z, lin2_w, lin2_b, (float*)d_out);
}

// Round 5
// 376.814 us; speedup vs baseline: 7.5295x; 1.0694x over previous
//
#include <hip/hip_runtime.h>

#define NN 50000
#define NE 400000
#define NG 256
#define BN_EPS 1e-5f
#define SCAN_E 8
#define SCAN_CHUNK 2048           // 256 threads * 8
#define SCAN_NB 25                // ceil(50000/2048)

typedef __attribute__((ext_vector_type(4))) float f32x4;
typedef __bf16 bf16x8 __attribute__((ext_vector_type(8)));
typedef __bf16 bf16x4 __attribute__((ext_vector_type(4)));

__device__ __forceinline__ void mfma_bf16(f32x4& d, bf16x8 a, bf16x8 b) {
  asm volatile("v_mfma_f32_16x16x32_bf16 %0, %1, %2, %0" : "+v"(d) : "v"(a), "v"(b));
}

// ---- W pre-split: wh/wl[n][k] = bf16 hi/lo of W[k][n], zero-padded to Kpad --
__global__ __launch_bounds__(256)
void wprep(const float* __restrict__ W, __bf16* __restrict__ wh,
           __bf16* __restrict__ wl, int K, int Kpad) {
  int idx = blockIdx.x * 256 + threadIdx.x;
  if (idx >= 128 * Kpad) return;
  int n = idx & 127, k = idx >> 7;
  float v = (k < K) ? W[(long)k * 128 + n] : 0.f;
  __bf16 h = (__bf16)v;
  wh[(long)n * Kpad + k] = h;
  wl[(long)n * Kpad + k] = (__bf16)(v - (float)h);
}

// ---- MFMA GEMM: C[M x 128] = A[M x K] @ W[K x 128], bf16x3 split ----------
// 512 thr = 8 waves (2x4), tile 64x128, each wave 32x32, BK=32.
// A_FP32: A is raw fp32 [M x Kact], split to hi/lo on the fly while staging.
// else:   A is pre-split bf16 planes [M x Kpad].
template<bool BIAS, bool RELU, bool OUT_SPLIT, bool A_FP32>
__global__ __launch_bounds__(512)
void gemm_bsp(const float* __restrict__ Af,
              const __bf16* __restrict__ Ah, const __bf16* __restrict__ Al,
              const __bf16* __restrict__ Wh, const __bf16* __restrict__ Wl,
              const float* __restrict__ bias, float* __restrict__ Cf,
              __bf16* __restrict__ Ch, __bf16* __restrict__ Cl,
              int M, int Kact, int Kpad) {
  __shared__ __align__(16) __bf16 ah[64 * 40];
  __shared__ __align__(16) __bf16 al[64 * 40];
  __shared__ __align__(16) __bf16 bh[128 * 40];
  __shared__ __align__(16) __bf16 bl[128 * 40];
  const int t = threadIdx.x;
  const int row0 = blockIdx.x * 64;
  const int wave = t >> 6, lane = t & 63;
  const int wr = wave >> 2, wc = wave & 3;   // 2x4 wave grid -> 32x32 tiles
  const int lr = lane & 15, kg = lane >> 4;

  // B staging: 128 rows x 4 k-octs, both planes per thread
  const int b_r = (t >> 2) & 127, b_ko = t & 3;
  const __bf16* bh_src = Wh + (long)b_r * Kpad + b_ko * 8;
  const __bf16* bl_src = Wl + (long)b_r * Kpad + b_ko * 8;
  __bf16* bh_dst = bh + b_r * 40 + b_ko * 8;
  __bf16* bl_dst = bl + b_r * 40 + b_ko * 8;

  f32x4 acc[2][2] = {};
  bf16x8 zero8;
#pragma unroll
  for (int j = 0; j < 8; ++j) zero8[j] = (__bf16)0.f;

  // ---- A staging setup + initial prefetch ----
  // plane path: 512 chunks = 2 planes x 64 rows x 4 k-octs
  const int a_pl = t >> 8, a_r8 = (t >> 2) & 63, a_ko = t & 3;
  const __bf16* a_src = (a_pl ? Al : Ah) + (long)(row0 + a_r8) * Kpad + a_ko * 8;
  __bf16* a_dst = (a_pl ? al : ah) + a_r8 * 40 + a_ko * 8;
  const bool a_ok8 = (row0 + a_r8) < M;
  // fp32 path: 64 rows x 8 k-quads(4 floats)
  const int a_rf = t >> 3, a_kq = t & 7;
  const bool a_okf = (row0 + a_rf) < M;
  const float* af_src = Af + (long)(row0 + a_rf) * Kact + a_kq * 4;
  __bf16* ahf_dst = ah + a_rf * 40 + a_kq * 4;
  __bf16* alf_dst = al + a_rf * 40 + a_kq * 4;

  bf16x8 av;
  float fa[4];
  if (A_FP32) {
#pragma unroll
    for (int j = 0; j < 4; ++j) {
      int k = a_kq * 4 + j;
      fa[j] = (a_okf && k < Kact) ? af_src[j] : 0.f;
    }
  } else {
    av = a_ok8 ? *(const bf16x8*)a_src : zero8;
  }
  bf16x8 bv0 = *(const bf16x8*)bh_src;
  bf16x8 bv1 = *(const bf16x8*)bl_src;

  for (int k0 = 0; k0 < Kpad; k0 += 32) {
    __syncthreads();
    if (A_FP32) {
      bf16x4 hv, lv;
#pragma unroll
      for (int j = 0; j < 4; ++j) {
        __bf16 h = (__bf16)fa[j];
        hv[j] = h; lv[j] = (__bf16)(fa[j] - (float)h);
      }
      *(bf16x4*)ahf_dst = hv;
      *(bf16x4*)alf_dst = lv;
    } else {
      *(bf16x8*)a_dst = av;
    }
    *(bf16x8*)bh_dst = bv0;
    *(bf16x8*)bl_dst = bv1;
    __syncthreads();
    int k1 = k0 + 32;
    if (k1 < Kpad) {            // prefetch next tile; overlaps MFMA below
      if (A_FP32) {
#pragma unroll
        for (int j = 0; j < 4; ++j) {
          int k = k1 + a_kq * 4 + j;
          fa[j] = (a_okf && k < Kact) ? af_src[k1 + j] : 0.f;
        }
      } else {
        av = a_ok8 ? *(const bf16x8*)(a_src + k1) : zero8;
      }
      bv0 = *(const bf16x8*)(bh_src + k1);
      bv1 = *(const bf16x8*)(bl_src + k1);
    }
    bf16x8 fah[2], fal[2], fbh[2], fbl[2];
#pragma unroll
    for (int mi = 0; mi < 2; ++mi) {
      int r = wr * 32 + mi * 16 + lr;
      fah[mi] = *(const bf16x8*)&ah[r * 40 + kg * 8];
      fal[mi] = *(const bf16x8*)&al[r * 40 + kg * 8];
    }
#pragma unroll
    for (int ni = 0; ni < 2; ++ni) {
      int c = wc * 32 + ni * 16 + lr;
      fbh[ni] = *(const bf16x8*)&bh[c * 40 + kg * 8];
      fbl[ni] = *(const bf16x8*)&bl[c * 40 + kg * 8];
    }
#pragma unroll
    for (int mi = 0; mi < 2; ++mi)
#pragma unroll
      for (int ni = 0; ni < 2; ++ni) {
        mfma_bf16(acc[mi][ni], fah[mi], fbh[ni]);
        mfma_bf16(acc[mi][ni], fal[mi], fbh[ni]);
        mfma_bf16(acc[mi][ni], fah[mi], fbl[ni]);
      }
  }
  // epilogue: C/D layout col=lane&15, row=(lane>>4)*4+reg
#pragma unroll
  for (int mi = 0; mi < 2; ++mi) {
#pragma unroll
    for (int ni = 0; ni < 2; ++ni) {
      int col = wc * 32 + ni * 16 + lr;
      float bv = BIAS ? bias[col] : 0.f;
#pragma unroll
      for (int r = 0; r < 4; ++r) {
        int row = row0 + wr * 32 + mi * 16 + kg * 4 + r;
        if (row < M) {
          float v = acc[mi][ni][r] + bv;
          if (RELU) v = fmaxf(v, 0.f);
          if (OUT_SPLIT) {
            __bf16 h = (__bf16)v;
            Ch[(long)row * 128 + col] = h;
            Cl[(long)row * 128 + col] = (__bf16)(v - (float)h);
          } else {
            Cf[(long)row * 128 + col] = v;
          }
        }
      }
    }
  }
}

// ---------------- CSR build -------------------------------------------------
__global__ __launch_bounds__(256)
void deg_count(const int* __restrict__ dst, int* __restrict__ deg, int E) {
  int e = blockIdx.x * 256 + threadIdx.x;
  if (e < E) atomicAdd(&deg[dst[e]], 1);
}

__global__ __launch_bounds__(256)
void scan_sums(const int* __restrict__ deg, int* __restrict__ bsum) {
  __shared__ int sm[256];
  int base = blockIdx.x * SCAN_CHUNK + threadIdx.x * SCAN_E;
  int s = 0;
#pragma unroll
  for (int k = 0; k < SCAN_E; ++k) { int i = base + k; if (i < NN) s += deg[i]; }
  sm[threadIdx.x] = s; __syncthreads();
  for (int off = 128; off > 0; off >>= 1) {
    if (threadIdx.x < off) sm[threadIdx.x] += sm[threadIdx.x + off];
    __syncthreads();
  }
  if (threadIdx.x == 0) bsum[blockIdx.x] = sm[0];
}

__global__ void scan_offs(const int* __restrict__ bsum, int* __restrict__ boff,
                          int* __restrict__ rowptr) {
  if (threadIdx.x == 0) {
    int run = 0;
    for (int i = 0; i < SCAN_NB; ++i) { boff[i] = run; run += bsum[i]; }
    rowptr[NN] = run;
  }
}

__global__ __launch_bounds__(256)
void scan_final(const int* __restrict__ boff, int* __restrict__ rowptr,
                int* __restrict__ cursor) {
  __shared__ int sm[256];
  int t = threadIdx.x;
  int base = blockIdx.x * SCAN_CHUNK + t * SCAN_E;
  int v[SCAN_E]; int s = 0;
#pragma unroll
  for (int k = 0; k < SCAN_E; ++k) { int i = base + k; v[k] = (i < NN) ? rowptr[i] : 0; s += v[k]; }
  sm[t] = s; __syncthreads();
  for (int off = 1; off < 256; off <<= 1) {
    int val = sm[t]; int add = (t >= off) ? sm[t - off] : 0;
    __syncthreads();
    sm[t] = val + add;
    __syncthreads();
  }
  int excl = (t == 0 ? 0 : sm[t - 1]) + boff[blockIdx.x];
#pragma unroll
  for (int k = 0; k < SCAN_E; ++k) {
    int i = base + k;
    if (i < NN) { rowptr[i] = excl; cursor[i] = excl; }
    excl += v[k];
  }
}

__global__ __launch_bounds__(256)
void scatter_csr(const int* __restrict__ src, const int* __restrict__ dst,
                 int* __restrict__ cursor, int* __restrict__ csr_src, int E) {
  int e = blockIdx.x * 256 + threadIdx.x;
  if (e < E) {
    int d = dst[e];
    int pos = atomicAdd(&cursor[d], 1);
    csr_src[pos] = src[e];
  }
}

// ---------------- fold BN params --------------------------------------------
__global__ void bn_prep(const float* __restrict__ b1, const float* __restrict__ g,
                        const float* __restrict__ bb, const float* __restrict__ m,
                        const float* __restrict__ v, float* __restrict__ scale,
                        float* __restrict__ shift) {
  int c = threadIdx.x;
  float s = g[c] * rsqrtf(v[c] + BN_EPS);
  scale[c] = s;
  shift[c] = (b1[c] - m[c]) * s + bb[c];
}

// ------- gather+sum over in-edges, fused BN+ReLU, emit split bf16 ----------
__global__ __launch_bounds__(256)
void gather_bn_split(const float* __restrict__ y, const int* __restrict__ rowptr,
                     const int* __restrict__ csr_src, const float* __restrict__ scale,
                     const float* __restrict__ shift, __bf16* __restrict__ oh,
                     __bf16* __restrict__ ol) {
  const int grp = threadIdx.x >> 5;
  const int lane = threadIdx.x & 31;
  const int node = blockIdx.x * 8 + grp;
  if (node >= NN) return;
  const float4* y4 = (const float4*)y;
  int s = rowptr[node], e = rowptr[node + 1];
  float4 acc = y4[(long)node * 32 + lane];
  float4 acc2 = {0.f, 0.f, 0.f, 0.f};
  int i = s;
  for (; i + 3 < e; i += 4) {
    int s0 = csr_src[i], s1 = csr_src[i + 1], s2 = csr_src[i + 2], s3 = csr_src[i + 3];
    float4 v0 = y4[(long)s0 * 32 + lane];
    float4 v1 = y4[(long)s1 * 32 + lane];
    float4 v2 = y4[(long)s2 * 32 + lane];
    float4 v3 = y4[(long)s3 * 32 + lane];
    acc.x += v0.x; acc.y += v0.y; acc.z += v0.z; acc.w += v0.w;
    acc2.x += v1.x; acc2.y += v1.y; acc2.z += v1.z; acc2.w += v1.w;
    acc.x += v2.x; acc.y += v2.y; acc.z += v2.z; acc.w += v2.w;
    acc2.x += v3.x; acc2.y += v3.y; acc2.z += v3.z; acc2.w += v3.w;
  }
  for (; i < e; ++i) {
    int sn = csr_src[i];
    float4 v = y4[(long)sn * 32 + lane];
    acc.x += v.x; acc.y += v.y; acc.z += v.z; acc.w += v.w;
  }
  acc.x += acc2.x; acc.y += acc2.y; acc.z += acc2.z; acc.w += acc2.w;
  float4 sc = ((const float4*)scale)[lane];
  float4 sh = ((const float4*)shift)[lane];
  float o0 = fmaxf(acc.x * sc.x + sh.x, 0.f);
  float o1 = fmaxf(acc.y * sc.y + sh.y, 0.f);
  float o2 = fmaxf(acc.z * sc.z + sh.z, 0.f);
  float o3 = fmaxf(acc.w * sc.w + sh.w, 0.f);
  __bf16 h0 = (__bf16)o0, h1 = (__bf16)o1, h2 = (__bf16)o2, h3 = (__bf16)o3;
  bf16x4 hv, lv;
  hv[0] = h0; hv[1] = h1; hv[2] = h2; hv[3] = h3;
  lv[0] = (__bf16)(o0 - (float)h0); lv[1] = (__bf16)(o1 - (float)h1);
  lv[2] = (__bf16)(o2 - (float)h2); lv[3] = (__bf16)(o3 - (float)h3);
  *(bf16x4*)&oh[(long)node * 128 + lane * 4] = hv;
  *(bf16x4*)&ol[(long)node * 128 + lane * 4] = lv;
}

// ---------------- graph boundaries / pooling / head ------------------------
__global__ void graph_bounds(const int* __restrict__ batch, int* __restrict__ gstart, int n) {
  int g = blockIdx.x * 64 + threadIdx.x;
  if (g > NG) return;
  int lo = 0, hi = n;
  while (lo < hi) {
    int mid = (lo + hi) >> 1;
    if (batch[mid] < g) lo = mid + 1; else hi = mid;
  }
  gstart[g] = lo;
}

// pooled from split planes; grid (NG, 3)
__global__ __launch_bounds__(128)
void pool_mean_split(const __bf16* __restrict__ h0h, const __bf16* __restrict__ h0l,
                     const __bf16* __restrict__ h1h, const __bf16* __restrict__ h1l,
                     const __bf16* __restrict__ h2h, const __bf16* __restrict__ h2l,
                     const int* __restrict__ gstart, float* __restrict__ pooled) {
  int layer = blockIdx.y;
  const __bf16* hh = (layer == 0) ? h0h : (layer == 1) ? h1h : h2h;
  const __bf16* hl = (layer == 0) ? h0l : (layer == 1) ? h1l : h2l;
  int g = blockIdx.x, c = threadIdx.x;
  int s = gstart[g], e = gstart[g + 1];
  float a0 = 0.f, a1 = 0.f, a2 = 0.f, a3 = 0.f;
  int i = s;
  for (; i + 3 < e; i += 4) {
    a0 += (float)hh[(long)i * 128 + c] + (float)hl[(long)i * 128 + c];
    a1 += (float)hh[(long)(i + 1) * 128 + c] + (float)hl[(long)(i + 1) * 128 + c];
    a2 += (float)hh[(long)(i + 2) * 128 + c] + (float)hl[(long)(i + 2) * 128 + c];
    a3 += (float)hh[(long)(i + 3) * 128 + c] + (float)hl[(long)(i + 3) * 128 + c];
  }
  for (; i < e; ++i)
    a0 += (float)hh[(long)i * 128 + c] + (float)hl[(long)i * 128 + c];
  float acc = (a0 + a1) + (a2 + a3);
  pooled[g * 384 + layer * 128 + c] = acc / fmaxf((float)(e - s), 1.f);
}

__global__ __launch_bounds__(384)
void lin1_k(const float* __restrict__ pooled, const float* __restrict__ w,
            const float* __restrict__ b, float* __restrict__ z) {
  __shared__ float pr[384];
  int mrow = blockIdx.x, t = threadIdx.x;
  pr[t] = pooled[mrow * 384 + t];
  __syncthreads();
  float acc = b[t];
  for (int k = 0; k < 384; ++k) acc += pr[k] * w[k * 384 + t];
  z[mrow * 384 + t] = fmaxf(acc, 0.f);
}

__global__ __launch_bounds__(192)
void lin2_k(const float* __restrict__ z, const float* __restrict__ w,
            const float* __restrict__ b, float* __restrict__ out) {
  int idx = blockIdx.x * 192 + threadIdx.x;
  if (idx >= NG * 3) return;
  int mrow = idx / 3, j = idx % 3;
  float acc = b[j];
  for (int k = 0; k < 384; ++k) acc += z[mrow * 384 + k] * w[k * 3 + j];
  out[idx] = acc;
}

extern "C" void kernel_launch(void* const* d_in, const int* in_sizes, int n_in,
                              void* d_out, int out_size, void* d_ws, size_t ws_size,
                              hipStream_t stream) {
  const float* x = (const float*)d_in[0];
  const int* ei = (const int*)d_in[1];
  const int* batch = (const int*)d_in[2];
  const int* srcv = ei;
  const int* dstv = ei + NE;
  const float* cw1[3] = {(const float*)d_in[3], (const float*)d_in[11], (const float*)d_in[19]};
  const float* cb1[3] = {(const float*)d_in[4], (const float*)d_in[12], (const float*)d_in[20]};
  const float* cg[3]  = {(const float*)d_in[5], (const float*)d_in[13], (const float*)d_in[21]};
  const float* cbb[3] = {(const float*)d_in[6], (const float*)d_in[14], (const float*)d_in[22]};
  const float* cm[3]  = {(const float*)d_in[7], (const float*)d_in[15], (const float*)d_in[23]};
  const float* cv[3]  = {(const float*)d_in[8], (const float*)d_in[16], (const float*)d_in[24]};
  const float* cw2[3] = {(const float*)d_in[9], (const float*)d_in[17], (const float*)d_in[25]};
  const float* cb2[3] = {(const float*)d_in[10], (const float*)d_in[18], (const float*)d_in[26]};
  const float* lin1_w = (const float*)d_in[27];
  const float* lin1_b = (const float*)d_in[28];
  const float* lin2_w = (const float*)d_in[29];
  const float* lin2_b = (const float*)d_in[30];

  const size_t NNF = (size_t)NN * 128;        // 6.4M
  float* wsf = (float*)d_ws;
  float* y = wsf;                              // [0, 6.4M) f32
  __bf16* Xb = (__bf16*)(wsf + NNF);           // bf16 plane region
  __bf16* gh = Xb;                             // gather split out, 6.4M bf16
  __bf16* gl = Xb + (size_t)6400000;
  __bf16* hh[3], *hl[3];
  for (int c = 0; c < 3; ++c) {
    hh[c] = Xb + (size_t)12800000 + (size_t)c * 12800000;
    hl[c] = hh[c] + (size_t)6400000;
  }
  float* misc = wsf + NNF + (size_t)25600000;  // after plane region (51.2M bf16)
  float* pooled = misc;                        // 256*384
  float* z      = pooled + (size_t)NG * 384;
  float* scale  = z + (size_t)NG * 384;        // 128
  float* shift  = scale + 128;
  __bf16* wth   = (__bf16*)(shift + 128);      // 128*544 bf16
  __bf16* wtl   = wth + (size_t)128 * 544;
  int* rowptr   = (int*)(wtl + (size_t)128 * 544);  // NN+1
  int* cursor   = rowptr + NN + 1;
  int* csr_src  = cursor + NN;
  int* bsum     = csr_src + NE;
  int* boff     = bsum + 32;
  int* gstart   = boff + 64;                   // 257

  // ---- build CSR (by dst) once ----
  hipMemsetAsync(rowptr, 0, (NN + 1) * sizeof(int), stream);
  deg_count<<<(NE + 255) / 256, 256, 0, stream>>>(dstv, rowptr, NE);
  scan_sums<<<SCAN_NB, 256, 0, stream>>>(rowptr, bsum);
  scan_offs<<<1, 64, 0, stream>>>(bsum, boff, rowptr);
  scan_final<<<SCAN_NB, 256, 0, stream>>>(boff, rowptr, cursor);
  scatter_csr<<<(NE + 255) / 256, 256, 0, stream>>>(srcv, dstv, cursor, csr_src, NE);

  const int gemm_grid = (NN + 63) / 64;        // 782
  for (int c = 0; c < 3; ++c) {
    int K = (c == 0) ? 513 : 128;
    int Kpad = (c == 0) ? 544 : 128;
    bn_prep<<<1, 128, 0, stream>>>(cb1[c], cg[c], cbb[c], cm[c], cv[c], scale, shift);
    wprep<<<(128 * Kpad + 255) / 256, 256, 0, stream>>>(cw1[c], wth, wtl, K, Kpad);
    if (c == 0)
      gemm_bsp<false, false, false, true><<<gemm_grid, 512, 0, stream>>>(
          x, nullptr, nullptr, wth, wtl, nullptr, y, nullptr, nullptr, NN, K, Kpad);
    else
      gemm_bsp<false, false, false, false><<<gemm_grid, 512, 0, stream>>>(
          nullptr, hh[c - 1], hl[c - 1], wth, wtl, nullptr, y, nullptr, nullptr, NN, K, Kpad);
    gather_bn_split<<<(NN + 7) / 8, 256, 0, stream>>>(y, rowptr, csr_src, scale, shift, gh, gl);
    wprep<<<(128 * 128 + 255) / 256, 256, 0, stream>>>(cw2[c], wth, wtl, 128, 128);
    gemm_bsp<true, true, true, false><<<gemm_grid, 512, 0, stream>>>(
        nullptr, gh, gl, wth, wtl, cb2[c], nullptr, hh[c], hl[c], NN, 128, 128);
  }
  graph_bounds<<<5, 64, 0, stream>>>(batch, gstart, NN);
  pool_mean_split<<<dim3(NG, 3), 128, 0, stream>>>(hh[0], hl[0], hh[1], hl[1], hh[2], hl[2],
                                                   gstart, pooled);
  lin1_k<<<NG, 384, 0, stream>>>(pooled, lin1_w, lin1_b, z);
  lin2_k<<<4, 192, 0, stream>>>(z, lin2_w, lin2_b, (float*)d_out);
}